// Round 4
// baseline (1031.415 us; speedup 1.0000x reference)
//
#include <hip/hip_runtime.h>
#include <hip/hip_bf16.h>
#include <cmath>
#include <cstdint>

#define B_ 8
#define S_ 1024
#define D_ 768
#define H_ 12
#define C_ 64
#define F_ 3072
#define NR (B_*S_)          // 8192 rows
#define LN_EPS 1e-5f

typedef unsigned short u16;                                  // bf16 bit-storage
typedef float  f32x4  __attribute__((ext_vector_type(4)));
typedef short  bf16x8 __attribute__((ext_vector_type(8)));   // 8 bf16 = 4 VGPR

__device__ __forceinline__ u16 f2bf(float f){
  __hip_bfloat16 h = __float2bfloat16(f);
  return *reinterpret_cast<u16*>(&h);
}

// async global->LDS, 16B per lane; LDS dest is wave-uniform base + lane*16
__device__ __forceinline__ void gload16(const void* g, void* l){
  __builtin_amdgcn_global_load_lds(
      (const __attribute__((address_space(1))) void*)g,
      (__attribute__((address_space(3))) void*)l, 16, 0, 0);
}

__device__ __forceinline__ void blk_reduce2(float& s, float& sq, float* red){
  #pragma unroll
  for (int o = 32; o > 0; o >>= 1){
    s  += __shfl_down(s,  o, 64);
    sq += __shfl_down(sq, o, 64);
  }
  int w = threadIdx.x >> 6;
  if ((threadIdx.x & 63) == 0){ red[w] = s; red[4+w] = sq; }
  __syncthreads();
  s  = red[0]+red[1]+red[2]+red[3];
  sq = red[4]+red[5]+red[6]+red[7];
}

// ---------------- LN: x -> n1 (bf16) ----------------
__global__ __launch_bounds__(256) void ln_kernel(const float* __restrict__ x,
    const float* __restrict__ g, const float* __restrict__ b,
    u16* __restrict__ n1){
  int row = blockIdx.x;
  size_t base = (size_t)row * D_;
  __shared__ float red[8];
  float v[3], s = 0.f, sq = 0.f;
  #pragma unroll
  for (int i = 0; i < 3; i++){
    int j = threadIdx.x + i*256;
    float t = x[base + j];
    v[i] = t; s += t; sq += t*t;
  }
  blk_reduce2(s, sq, red);
  float mean = s * (1.f/D_);
  float var  = sq * (1.f/D_) - mean*mean;
  float rstd = rsqrtf(var + LN_EPS);
  #pragma unroll
  for (int i = 0; i < 3; i++){
    int j = threadIdx.x + i*256;
    n1[base + j] = f2bf((v[i]-mean)*rstd*g[j] + b[j]);
  }
}

// ---------- middle = x + attn -> d_out(fp32);  LN(middle) -> n2 (bf16) ----------
__global__ __launch_bounds__(256) void midln_kernel(const float* __restrict__ x,
    const float* __restrict__ attn, const float* __restrict__ g,
    const float* __restrict__ b, float* __restrict__ mid, u16* __restrict__ n2){
  int row = blockIdx.x;
  size_t base = (size_t)row * D_;
  __shared__ float red[8];
  float v[3], s = 0.f, sq = 0.f;
  #pragma unroll
  for (int i = 0; i < 3; i++){
    int j = threadIdx.x + i*256;
    float t = x[base + j] + attn[base + j];
    mid[base + j] = t;
    v[i] = t; s += t; sq += t*t;
  }
  blk_reduce2(s, sq, red);
  float mean = s * (1.f/D_);
  float var  = sq * (1.f/D_) - mean*mean;
  float rstd = rsqrtf(var + LN_EPS);
  #pragma unroll
  for (int i = 0; i < 3; i++){
    int j = threadIdx.x + i*256;
    n2[base + j] = f2bf((v[i]-mean)*rstd*g[j] + b[j]);
  }
}

// ---------------- W[K][N] fp32 -> Wt[N][K] bf16 ----------------
__global__ void transpose_cast(const float* __restrict__ W, u16* __restrict__ Wt,
                               int K, int N){
  __shared__ float t[32][33];
  int n0 = blockIdx.x*32, k0 = blockIdx.y*32;
  for (int i = threadIdx.y; i < 32; i += 8)
    t[i][threadIdx.x] = W[(size_t)(k0+i)*N + n0 + threadIdx.x];
  __syncthreads();
  for (int i = threadIdx.y; i < 32; i += 8)
    Wt[(size_t)(n0+i)*K + k0 + threadIdx.x] = f2bf(t[threadIdx.x][i]);
}

// ---------------- per-head QKV projection (MFMA) ----------------
__global__ __launch_bounds__(256) void qkv_kernel(const u16* __restrict__ n1,
    const float* __restrict__ Wq, const float* __restrict__ bq,
    const float* __restrict__ Wk, const float* __restrict__ bk,
    const float* __restrict__ Wv, const float* __restrict__ bv,
    u16* __restrict__ q, u16* __restrict__ k, u16* __restrict__ v){
  int rt = blockIdx.x;           // 128 row-tiles of 64 rows
  int h  = blockIdx.y;           // head
  int tid = threadIdx.x, lane = tid & 63, wid = tid >> 6;
  __shared__ __align__(16) u16 Xs[4096];       // [8 kc][64 m][8]
  __shared__ __align__(16) u16 Ws[3*4096];     // per mat: [8 kc(d)][64 c][8]

  #pragma unroll
  for (int mat = 0; mat < 3; mat++){
    const float* Wh = (mat==0?Wq:(mat==1?Wk:Wv)) + (size_t)h*4096;
    for (int e = 0; e < 16; e++){
      int flat = e*256 + tid;            // d*64+c
      int d = flat >> 6, c = flat & 63;
      Ws[mat*4096 + (d>>3)*512 + c*8 + (d&7)] = f2bf(Wh[flat]);
    }
  }
  for (int r = 0; r < 2; r++){
    int u0 = (r*4 + wid)*64;
    int u = u0 + lane, kc = u >> 6, m = u & 63;
    gload16(n1 + (size_t)(rt*64 + m)*D_ + h*64 + kc*8, &Xs[u0*8]);
  }
  __syncthreads();

  f32x4 acc[4][3];
  #pragma unroll
  for (int mi=0; mi<4; mi++)
    #pragma unroll
    for (int ni=0; ni<3; ni++) acc[mi][ni] = (f32x4){0.f,0.f,0.f,0.f};

  #pragma unroll
  for (int ks = 0; ks < 2; ks++){
    int kc = ks*4 + (lane >> 4);
    bf16x8 a[4], bfr[3];
    #pragma unroll
    for (int mi=0; mi<4; mi++)
      a[mi] = *(const bf16x8*)&Xs[kc*512 + (mi*16 + (lane&15))*8];
    #pragma unroll
    for (int ni=0; ni<3; ni++){
      int co = wid*48 + ni*16 + (lane&15);   // col in concat(q,k,v) 0..191
      int mat = co >> 6, c = co & 63;
      bfr[ni] = *(const bf16x8*)&Ws[mat*4096 + kc*512 + c*8];
    }
    #pragma unroll
    for (int mi=0; mi<4; mi++)
      #pragma unroll
      for (int ni=0; ni<3; ni++)
        acc[mi][ni] = __builtin_amdgcn_mfma_f32_16x16x32_bf16(a[mi], bfr[ni], acc[mi][ni], 0,0,0);
  }

  #pragma unroll
  for (int ni=0; ni<3; ni++){
    int co = wid*48 + ni*16 + (lane&15);
    int mat = co >> 6, c = co & 63;
    u16* outp = mat==0 ? q : (mat==1 ? k : v);
    const float* bias = mat==0 ? bq : (mat==1 ? bk : bv);
    float bb = bias[h*64 + c];
    #pragma unroll
    for (int mi=0; mi<4; mi++){
      #pragma unroll
      for (int r=0; r<4; r++){
        int grow = rt*64 + mi*16 + (lane>>4)*4 + r;   // 0..8191
        int b_ = grow >> 10, s = grow & 1023;
        outp[(((size_t)b_*H_ + h)*S_ + s)*C_ + c] = f2bf(acc[mi][ni][r] + bb);
      }
    }
  }
}

// ---------------- flash attention (bf16 MFMA, fp32 online softmax) ----------------
__global__ __launch_bounds__(256) void attn_kernel(const u16* __restrict__ q,
    const u16* __restrict__ k, const u16* __restrict__ v, float* __restrict__ attn){
  int qt = blockIdx.x, bh = blockIdx.y;
  int tid = threadIdx.x, lane = tid & 63, wid = tid >> 6;
  __shared__ __align__(16) u16 Qs[4096], Ks[4096], Vt[4096], Ps[4096];
  const u16* qh = q + (size_t)bh*S_*C_;
  const u16* kh = k + (size_t)bh*S_*C_;
  const u16* vh = v + (size_t)bh*S_*C_;

  for (int r = 0; r < 2; r++){
    int u0 = (r*4 + wid)*64;
    int u = u0 + lane, kc = u >> 6, m = u & 63;
    gload16(qh + (size_t)(qt*64 + m)*C_ + kc*8, &Qs[u0*8]);
  }

  f32x4 o[4];
  #pragma unroll
  for (int ci=0; ci<4; ci++) o[ci] = (f32x4){0.f,0.f,0.f,0.f};
  float mrow[4] = {-1e30f,-1e30f,-1e30f,-1e30f};
  float lrow[4] = {0.f,0.f,0.f,0.f};

  for (int kt = 0; kt < S_/64; kt++){
    __syncthreads();
    for (int r = 0; r < 2; r++){
      int u0 = (r*4 + wid)*64;
      int u = u0 + lane, kc = u >> 6, m = u & 63;
      gload16(kh + (size_t)(kt*64 + m)*C_ + kc*8, &Ks[u0*8]);
    }
    for (int i = 0; i < 2; i++){
      int cc = i*256 + tid;                 // 512 chunks of 8
      int kk2 = cc >> 3, c0 = (cc & 7)*8;
      bf16x8 vv8 = *(const bf16x8*)&vh[(size_t)(kt*64 + kk2)*C_ + c0];
      #pragma unroll
      for (int j = 0; j < 8; j++)
        Vt[(kk2>>3)*512 + (c0+j)*8 + (kk2&7)] = ((const u16*)&vv8)[j];
    }
    __syncthreads();

    f32x4 sfr[4];
    #pragma unroll
    for (int ni=0; ni<4; ni++) sfr[ni] = (f32x4){0.f,0.f,0.f,0.f};
    #pragma unroll
    for (int ks = 0; ks < 2; ks++){
      int kc = ks*4 + (lane >> 4);
      bf16x8 afr = *(const bf16x8*)&Qs[kc*512 + (wid*16 + (lane&15))*8];
      #pragma unroll
      for (int ni=0; ni<4; ni++){
        bf16x8 bfr = *(const bf16x8*)&Ks[kc*512 + (ni*16 + (lane&15))*8];
        sfr[ni] = __builtin_amdgcn_mfma_f32_16x16x32_bf16(afr, bfr, sfr[ni], 0,0,0);
      }
    }

    float alpha[4];
    #pragma unroll
    for (int r = 0; r < 4; r++){
      float mx = -1e30f;
      #pragma unroll
      for (int ni=0; ni<4; ni++){ sfr[ni][r] *= 0.125f; mx = fmaxf(mx, sfr[ni][r]); }
      #pragma unroll
      for (int off = 1; off < 16; off <<= 1) mx = fmaxf(mx, __shfl_xor(mx, off, 64));
      float mnew = fmaxf(mrow[r], mx);
      alpha[r] = __expf(mrow[r] - mnew);
      mrow[r] = mnew;
      float rs = 0.f;
      #pragma unroll
      for (int ni=0; ni<4; ni++){
        float p = __expf(sfr[ni][r] - mnew);
        sfr[ni][r] = p; rs += p;
      }
      #pragma unroll
      for (int off = 1; off < 16; off <<= 1) rs += __shfl_xor(rs, off, 64);
      lrow[r] = lrow[r]*alpha[r] + rs;
    }
    #pragma unroll
    for (int ci=0; ci<4; ci++)
      #pragma unroll
      for (int r=0; r<4; r++) o[ci][r] *= alpha[r];

    #pragma unroll
    for (int ni=0; ni<4; ni++){
      int kcol = ni*16 + (lane&15);
      int kc = kcol >> 3, krm = kcol & 7;
      #pragma unroll
      for (int r=0; r<4; r++){
        int qrow = wid*16 + (lane>>4)*4 + r;
        Ps[kc*512 + qrow*8 + krm] = f2bf(sfr[ni][r]);
      }
    }
    #pragma unroll
    for (int ks = 0; ks < 2; ks++){
      int kc = ks*4 + (lane >> 4);
      bf16x8 afr = *(const bf16x8*)&Ps[kc*512 + (wid*16 + (lane&15))*8];
      #pragma unroll
      for (int ci=0; ci<4; ci++){
        bf16x8 bfr = *(const bf16x8*)&Vt[kc*512 + (ci*16 + (lane&15))*8];
        o[ci] = __builtin_amdgcn_mfma_f32_16x16x32_bf16(afr, bfr, o[ci], 0,0,0);
      }
    }
  }

  int b_ = bh / H_, h = bh % H_;
  #pragma unroll
  for (int ci=0; ci<4; ci++){
    int d = h*64 + ci*16 + (lane&15);
    #pragma unroll
    for (int r=0; r<4; r++){
      int srow = qt*64 + wid*16 + (lane>>4)*4 + r;
      attn[((size_t)b_*S_ + srow)*D_ + d] = o[ci][r] / lrow[r];
    }
  }
}

// ============ 256x256 GEMM: C[M,N] = A[M,K]*Bt[N,K]^T + bias ============
// BK=32, ring-3 LDS (96KB, 1 block/CU, 8 waves 2Mx4N, wave tile 128x64).
// Counted vmcnt(4) with 2-phase latency cover; clamp-restage tail keeps the
// wait value uniform. Ring safety: slot staged at P(k) was last read at
// P(k-1), whose reads retired before its own lgkmcnt(0)->MFMA->barrier.
// 2D XCD patches: xcd = bid&7 owns a PMxPN tile patch, bm swept fastest so
// the 1.5MB B-panel stays L2-resident per XCD.
// EPI 0: gelu(exact) -> bf16    EPI 1: + addin(fp32) -> fp32
template<int K_, int EPI, int PM, int PN, int PGN>
__global__ __launch_bounds__(512, 2) void gemm256_kernel(
    const u16* __restrict__ A, const u16* __restrict__ Bt,
    const float* __restrict__ bias, void* __restrict__ outp,
    const float* __restrict__ addin, int N){
  constexpr int NT = K_/32;                     // K-steps
  __shared__ __align__(16) u16 As[3*8192];      // [slot][4 kc][256 m][8]  48KB
  __shared__ __align__(16) u16 Bs[3*8192];      // [slot][4 kc][256 n][8]  48KB
  int tid = threadIdx.x, lane = tid & 63, wid = tid >> 6;
  int wm = wid >> 2, wn = wid & 3;              // 2x4 waves
  int bid = blockIdx.x;
  int j = bid >> 3, xcd = bid & 7;
  int bm = (xcd/PGN)*PM + (j - (j/PM)*PM);
  int bn = (xcd - (xcd/PGN)*PGN)*PN + (j/PM);
  const u16* Ab = A  + (size_t)bm*256*K_;
  const u16* Bb = Bt + (size_t)bn*256*K_;

  auto stage = [&](int slot, int kt){           // 4 gloads/thread (A:2, B:2)
    #pragma unroll
    for (int r = 0; r < 2; r++){
      int u0 = r*512 + wid*64;
      int kc0 = u0 >> 8, m0 = u0 & 255;
      gload16(Ab + (size_t)(m0+lane)*K_ + kt*32 + kc0*8,
              &As[slot*8192 + kc0*2048 + m0*8]);
      gload16(Bb + (size_t)(m0+lane)*K_ + kt*32 + kc0*8,
              &Bs[slot*8192 + kc0*2048 + m0*8]);
    }
  };

  f32x4 acc[8][4];
  #pragma unroll
  for (int mi=0; mi<8; mi++)
    #pragma unroll
    for (int ni=0; ni<4; ni++) acc[mi][ni] = (f32x4){0.f,0.f,0.f,0.f};

  // prologue: slot0 <- step0, slot1 <- step1; drain batch0
  stage(0, 0); stage(1, 1);
  asm volatile("s_waitcnt vmcnt(4)" ::: "memory");
  __builtin_amdgcn_s_barrier();

  for (int k = 0; k < NT; k++){
    int slot = k - (k/3)*3;                     // k % 3
    int snx  = (k+2) - ((k+2)/3)*3;             // (k+2) % 3
    int ksrc = (k+2 < NT) ? (k+2) : (NT-1);     // clamp-restage at tail
    stage(snx, ksrc);

    bf16x8 af[8], bfv[4];
    int kc = lane >> 4;
    #pragma unroll
    for (int mi=0; mi<8; mi++)
      af[mi] = *(const bf16x8*)&As[slot*8192 + kc*2048 + (wm*128 + mi*16 + (lane&15))*8];
    #pragma unroll
    for (int ni=0; ni<4; ni++)
      bfv[ni] = *(const bf16x8*)&Bs[slot*8192 + kc*2048 + (wn*64 + ni*16 + (lane&15))*8];
    asm volatile("s_waitcnt lgkmcnt(0)" ::: "memory");
    __builtin_amdgcn_sched_barrier(0);
    __builtin_amdgcn_s_setprio(1);
    #pragma unroll
    for (int mi=0; mi<8; mi++)
      #pragma unroll
      for (int ni=0; ni<4; ni++)
        acc[mi][ni] = __builtin_amdgcn_mfma_f32_16x16x32_bf16(af[mi], bfv[ni], acc[mi][ni], 0,0,0);
    __builtin_amdgcn_s_setprio(0);
    asm volatile("s_waitcnt vmcnt(4)" ::: "memory");   // drain batch k+1 for next phase
    __builtin_amdgcn_s_barrier();
  }

  int gm0 = bm*256 + wm*128, gn0 = bn*256 + wn*64;
  #pragma unroll
  for (int mi=0; mi<8; mi++){
    #pragma unroll
    for (int ni=0; ni<4; ni++){
      int gn = gn0 + ni*16 + (lane&15);
      float bb = bias[gn];
      #pragma unroll
      for (int r=0; r<4; r++){
        int gm = gm0 + mi*16 + (lane>>4)*4 + r;
        float val = acc[mi][ni][r] + bb;
        if (EPI == 0){
          float ge = 0.5f*val*(1.f + erff(val*0.70710678118f));
          ((u16*)outp)[(size_t)gm*N + gn] = f2bf(ge);
        } else {
          ((float*)outp)[(size_t)gm*N + gn] = val + addin[(size_t)gm*N + gn];
        }
      }
    }
  }
}

extern "C" void kernel_launch(void* const* d_in, const int* in_sizes, int n_in,
                              void* d_out, int out_size, void* d_ws, size_t ws_size,
                              hipStream_t stream) {
  const float* x   = (const float*)d_in[0];
  const float* lng = (const float*)d_in[1];
  const float* lnb = (const float*)d_in[2];
  const float* Wq  = (const float*)d_in[3];
  const float* bq  = (const float*)d_in[4];
  const float* Wk  = (const float*)d_in[5];
  const float* bk  = (const float*)d_in[6];
  const float* Wv  = (const float*)d_in[7];
  const float* bv  = (const float*)d_in[8];
  const float* W1  = (const float*)d_in[9];
  const float* b1  = (const float*)d_in[10];
  const float* Wm  = (const float*)d_in[11];
  const float* bm  = (const float*)d_in[12];
  const float* W2  = (const float*)d_in[13];
  const float* b2  = (const float*)d_in[14];
  float* out = (float*)d_out;

  char* ws = (char*)d_ws;
  const size_t MB = 1024*1024;
  u16*   n1  = (u16*)(ws + 0);          // 12 MiB  (reused as n2)
  u16*   qq  = (u16*)(ws + 12*MB);      // 12 MiB
  u16*   kk  = (u16*)(ws + 24*MB);      // 12 MiB
  u16*   vv  = (u16*)(ws + 36*MB);      // 12 MiB
  float* at  = (float*)(ws + 48*MB);    // 24 MiB
  u16*   h1  = (u16*)(ws + 12*MB);      // 48 MiB (overlays q/k/v+attn, dead by then)
  u16*   h2  = (u16*)(ws + 72*MB);      // 48 MiB
  u16*   w1t = (u16*)(ws + 120*MB);     // 4.5 MiB  [F][D]
  u16*   wmt = (u16*)(ws + 125*MB);     // 18 MiB   [F][F]
  u16*   w2t = (u16*)(ws + 144*MB);     // 4.5 MiB  [D][F]  (total 148.5 MiB)

  transpose_cast<<<dim3(F_/32, D_/32), dim3(32,8), 0, stream>>>(W1, w1t, D_, F_);
  transpose_cast<<<dim3(F_/32, F_/32), dim3(32,8), 0, stream>>>(Wm, wmt, F_, F_);
  transpose_cast<<<dim3(D_/32, F_/32), dim3(32,8), 0, stream>>>(W2, w2t, F_, D_);

  ln_kernel<<<NR, 256, 0, stream>>>(x, lng, lnb, n1);
  qkv_kernel<<<dim3(NR/64, H_), 256, 0, stream>>>(n1, Wq, bq, Wk, bk, Wv, bv, qq, kk, vv);
  attn_kernel<<<dim3(S_/64, B_*H_), 256, 0, stream>>>(qq, kk, vv, at);
  midln_kernel<<<NR, 256, 0, stream>>>(x, at, lng, lnb, out, n1 /*=n2*/);

  // M=8192 -> Mt=32 tiles; N=3072 -> Nt=12 (patch 8x6, PGN=2); N=768 -> Nt=3 (patch 4x3, PGN=1)
  gemm256_kernel<768, 0, 8, 6, 2><<<384, 512, 0, stream>>>(n1, w1t, b1, h1, nullptr, F_);
  gemm256_kernel<3072,0, 8, 6, 2><<<384, 512, 0, stream>>>(h1, wmt, bm, h2, nullptr, F_);
  gemm256_kernel<3072,1, 4, 3, 1><<<96,  512, 0, stream>>>(h2, w2t, b2, out, out, D_);
}

// Round 7
// 774.980 us; speedup vs baseline: 1.3309x; 1.3309x over previous
//
#include <hip/hip_runtime.h>
#include <hip/hip_bf16.h>
#include <cmath>
#include <cstdint>

#define B_ 8
#define S_ 1024
#define D_ 768
#define H_ 12
#define C_ 64
#define F_ 3072
#define NR (B_*S_)          // 8192 rows
#define LN_EPS 1e-5f

typedef unsigned short u16;                                  // bf16 bit-storage
typedef float  f32x4  __attribute__((ext_vector_type(4)));
typedef short  bf16x8 __attribute__((ext_vector_type(8)));   // 8 bf16 = 4 VGPR

__device__ __forceinline__ u16 f2bf(float f){
  __hip_bfloat16 h = __float2bfloat16(f);
  return *reinterpret_cast<u16*>(&h);
}

// Tiled operand layout: global image == LDS staging image, so GEMM staging is
// a linear 16KB chunk copy (100% cache-line utilization; round-4 row-scatter
// used 16B of each 128B line = the 8x fabric over-fetch that limited us).
// offset(m,k) = panel(m)*256K + kstep(k)*8192 + kc(k)*2048 + (m%256)*8 + k%8
__device__ __forceinline__ size_t toff(int m, int k, int K){
  return (size_t)(m>>8)*((size_t)K*256) + (size_t)(k>>5)*8192
       + (size_t)((k>>3)&3)*2048 + (size_t)(m&255)*8 + (size_t)(k&7);
}

// async global->LDS, 16B per lane; LDS dest is wave-uniform base + lane*16
__device__ __forceinline__ void gload16(const void* g, void* l){
  __builtin_amdgcn_global_load_lds(
      (const __attribute__((address_space(1))) void*)g,
      (__attribute__((address_space(3))) void*)l, 16, 0, 0);
}

__device__ __forceinline__ void blk_reduce2(float& s, float& sq, float* red){
  #pragma unroll
  for (int o = 32; o > 0; o >>= 1){
    s  += __shfl_down(s,  o, 64);
    sq += __shfl_down(sq, o, 64);
  }
  int w = threadIdx.x >> 6;
  if ((threadIdx.x & 63) == 0){ red[w] = s; red[4+w] = sq; }
  __syncthreads();
  s  = red[0]+red[1]+red[2]+red[3];
  sq = red[4]+red[5]+red[6]+red[7];
}

// ---------------- LN: x -> n1 (bf16, tiled K=768) ----------------
__global__ __launch_bounds__(256) void ln_kernel(const float* __restrict__ x,
    const float* __restrict__ g, const float* __restrict__ b,
    u16* __restrict__ n1){
  int row = blockIdx.x;
  size_t base = (size_t)row * D_;
  __shared__ float red[8];
  float v[3], s = 0.f, sq = 0.f;
  #pragma unroll
  for (int i = 0; i < 3; i++){
    int j = threadIdx.x + i*256;
    float t = x[base + j];
    v[i] = t; s += t; sq += t*t;
  }
  blk_reduce2(s, sq, red);
  float mean = s * (1.f/D_);
  float var  = sq * (1.f/D_) - mean*mean;
  float rstd = rsqrtf(var + LN_EPS);
  #pragma unroll
  for (int i = 0; i < 3; i++){
    int j = threadIdx.x + i*256;
    n1[toff(row, j, D_)] = f2bf((v[i]-mean)*rstd*g[j] + b[j]);
  }
}

// ---- middle = x + attn -> d_out(fp32);  LN(middle) -> n2 (bf16, tiled) ----
__global__ __launch_bounds__(256) void midln_kernel(const float* __restrict__ x,
    const float* __restrict__ attn, const float* __restrict__ g,
    const float* __restrict__ b, float* __restrict__ mid, u16* __restrict__ n2){
  int row = blockIdx.x;
  size_t base = (size_t)row * D_;
  __shared__ float red[8];
  float v[3], s = 0.f, sq = 0.f;
  #pragma unroll
  for (int i = 0; i < 3; i++){
    int j = threadIdx.x + i*256;
    float t = x[base + j] + attn[base + j];
    mid[base + j] = t;
    v[i] = t; s += t; sq += t*t;
  }
  blk_reduce2(s, sq, red);
  float mean = s * (1.f/D_);
  float var  = sq * (1.f/D_) - mean*mean;
  float rstd = rsqrtf(var + LN_EPS);
  #pragma unroll
  for (int i = 0; i < 3; i++){
    int j = threadIdx.x + i*256;
    n2[toff(row, j, D_)] = f2bf((v[i]-mean)*rstd*g[j] + b[j]);
  }
}

// ------------- W[K][N] fp32 -> Wt tiled [N][K] bf16 -------------
__global__ void transpose_cast(const float* __restrict__ W, u16* __restrict__ Wt,
                               int K, int N){
  __shared__ float t[32][33];
  int n0 = blockIdx.x*32, k0 = blockIdx.y*32;
  for (int i = threadIdx.y; i < 32; i += 8)
    t[i][threadIdx.x] = W[(size_t)(k0+i)*N + n0 + threadIdx.x];
  __syncthreads();
  for (int i = threadIdx.y; i < 32; i += 8)
    Wt[toff(n0+i, k0+threadIdx.x, K)] = f2bf(t[threadIdx.x][i]);
}

// ---------------- per-head QKV projection (MFMA) ----------------
// reads n1 in tiled layout (linear 16B granules per wave-call)
__global__ __launch_bounds__(256) void qkv_kernel(const u16* __restrict__ n1,
    const float* __restrict__ Wq, const float* __restrict__ bq,
    const float* __restrict__ Wk, const float* __restrict__ bk,
    const float* __restrict__ Wv, const float* __restrict__ bv,
    u16* __restrict__ q, u16* __restrict__ k, u16* __restrict__ v){
  int rt = blockIdx.x;           // 128 row-tiles of 64 rows
  int h  = blockIdx.y;           // head
  int tid = threadIdx.x, lane = tid & 63, wid = tid >> 6;
  __shared__ __align__(16) u16 Xs[4096];       // [8 kc][64 m][8]
  __shared__ __align__(16) u16 Ws[3*4096];     // per mat: [8 kc(d)][64 c][8]

  #pragma unroll
  for (int mat = 0; mat < 3; mat++){
    const float* Wh = (mat==0?Wq:(mat==1?Wk:Wv)) + (size_t)h*4096;
    for (int e = 0; e < 16; e++){
      int flat = e*256 + tid;            // d*64+c
      int d = flat >> 6, c = flat & 63;
      Ws[mat*4096 + (d>>3)*512 + c*8 + (d&7)] = f2bf(Wh[flat]);
    }
  }
  // X tile rows rt*64..rt*64+63, cols h*64+kc*8..+7 from tiled n1
  for (int r = 0; r < 2; r++){
    int u0 = (r*4 + wid)*64;
    int kc = u0 >> 6;                    // uniform per call; m = lane
    gload16(n1 + (size_t)(rt>>2)*196608 + (size_t)(h*2 + (kc>>2))*8192
               + (size_t)(kc&3)*2048 + (size_t)((rt&3)*64 + lane)*8,
            &Xs[u0*8]);
  }
  __syncthreads();

  f32x4 acc[4][3];
  #pragma unroll
  for (int mi=0; mi<4; mi++)
    #pragma unroll
    for (int ni=0; ni<3; ni++) acc[mi][ni] = (f32x4){0.f,0.f,0.f,0.f};

  #pragma unroll
  for (int ks = 0; ks < 2; ks++){
    int kc = ks*4 + (lane >> 4);
    bf16x8 a[4], bfr[3];
    #pragma unroll
    for (int mi=0; mi<4; mi++)
      a[mi] = *(const bf16x8*)&Xs[kc*512 + (mi*16 + (lane&15))*8];
    #pragma unroll
    for (int ni=0; ni<3; ni++){
      int co = wid*48 + ni*16 + (lane&15);   // col in concat(q,k,v) 0..191
      int mat = co >> 6, c = co & 63;
      bfr[ni] = *(const bf16x8*)&Ws[mat*4096 + kc*512 + c*8];
    }
    #pragma unroll
    for (int mi=0; mi<4; mi++)
      #pragma unroll
      for (int ni=0; ni<3; ni++)
        acc[mi][ni] = __builtin_amdgcn_mfma_f32_16x16x32_bf16(a[mi], bfr[ni], acc[mi][ni], 0,0,0);
  }

  #pragma unroll
  for (int ni=0; ni<3; ni++){
    int co = wid*48 + ni*16 + (lane&15);
    int mat = co >> 6, c = co & 63;
    u16* outp = mat==0 ? q : (mat==1 ? k : v);
    const float* bias = mat==0 ? bq : (mat==1 ? bk : bv);
    float bb = bias[h*64 + c];
    #pragma unroll
    for (int mi=0; mi<4; mi++){
      #pragma unroll
      for (int r=0; r<4; r++){
        int grow = rt*64 + mi*16 + (lane>>4)*4 + r;   // 0..8191
        int b_ = grow >> 10, s = grow & 1023;
        outp[(((size_t)b_*H_ + h)*S_ + s)*C_ + c] = f2bf(acc[mi][ni][r] + bb);
      }
    }
  }
}

// ---------------- flash attention (bf16 MFMA, fp32 online softmax) ----------------
__global__ __launch_bounds__(256) void attn_kernel(const u16* __restrict__ q,
    const u16* __restrict__ k, const u16* __restrict__ v, float* __restrict__ attn){
  int qt = blockIdx.x, bh = blockIdx.y;
  int tid = threadIdx.x, lane = tid & 63, wid = tid >> 6;
  __shared__ __align__(16) u16 Qs[4096], Ks[4096], Vt[4096], Ps[4096];
  const u16* qh = q + (size_t)bh*S_*C_;
  const u16* kh = k + (size_t)bh*S_*C_;
  const u16* vh = v + (size_t)bh*S_*C_;

  for (int r = 0; r < 2; r++){
    int u0 = (r*4 + wid)*64;
    int u = u0 + lane, kc = u >> 6, m = u & 63;
    gload16(qh + (size_t)(qt*64 + m)*C_ + kc*8, &Qs[u0*8]);
  }

  f32x4 o[4];
  #pragma unroll
  for (int ci=0; ci<4; ci++) o[ci] = (f32x4){0.f,0.f,0.f,0.f};
  float mrow[4] = {-1e30f,-1e30f,-1e30f,-1e30f};
  float lrow[4] = {0.f,0.f,0.f,0.f};

  for (int kt = 0; kt < S_/64; kt++){
    __syncthreads();
    for (int r = 0; r < 2; r++){
      int u0 = (r*4 + wid)*64;
      int u = u0 + lane, kc = u >> 6, m = u & 63;
      gload16(kh + (size_t)(kt*64 + m)*C_ + kc*8, &Ks[u0*8]);
    }
    for (int i = 0; i < 2; i++){
      int cc = i*256 + tid;                 // 512 chunks of 8
      int kk2 = cc >> 3, c0 = (cc & 7)*8;
      bf16x8 vv8 = *(const bf16x8*)&vh[(size_t)(kt*64 + kk2)*C_ + c0];
      #pragma unroll
      for (int j = 0; j < 8; j++)
        Vt[(kk2>>3)*512 + (c0+j)*8 + (kk2&7)] = ((const u16*)&vv8)[j];
    }
    __syncthreads();

    f32x4 sfr[4];
    #pragma unroll
    for (int ni=0; ni<4; ni++) sfr[ni] = (f32x4){0.f,0.f,0.f,0.f};
    #pragma unroll
    for (int ks = 0; ks < 2; ks++){
      int kc = ks*4 + (lane >> 4);
      bf16x8 afr = *(const bf16x8*)&Qs[kc*512 + (wid*16 + (lane&15))*8];
      #pragma unroll
      for (int ni=0; ni<4; ni++){
        bf16x8 bfr = *(const bf16x8*)&Ks[kc*512 + (ni*16 + (lane&15))*8];
        sfr[ni] = __builtin_amdgcn_mfma_f32_16x16x32_bf16(afr, bfr, sfr[ni], 0,0,0);
      }
    }

    float alpha[4];
    #pragma unroll
    for (int r = 0; r < 4; r++){
      float mx = -1e30f;
      #pragma unroll
      for (int ni=0; ni<4; ni++){ sfr[ni][r] *= 0.125f; mx = fmaxf(mx, sfr[ni][r]); }
      #pragma unroll
      for (int off = 1; off < 16; off <<= 1) mx = fmaxf(mx, __shfl_xor(mx, off, 64));
      float mnew = fmaxf(mrow[r], mx);
      alpha[r] = __expf(mrow[r] - mnew);
      mrow[r] = mnew;
      float rs = 0.f;
      #pragma unroll
      for (int ni=0; ni<4; ni++){
        float p = __expf(sfr[ni][r] - mnew);
        sfr[ni][r] = p; rs += p;
      }
      #pragma unroll
      for (int off = 1; off < 16; off <<= 1) rs += __shfl_xor(rs, off, 64);
      lrow[r] = lrow[r]*alpha[r] + rs;
    }
    #pragma unroll
    for (int ci=0; ci<4; ci++)
      #pragma unroll
      for (int r=0; r<4; r++) o[ci][r] *= alpha[r];

    #pragma unroll
    for (int ni=0; ni<4; ni++){
      int kcol = ni*16 + (lane&15);
      int kc = kcol >> 3, krm = kcol & 7;
      #pragma unroll
      for (int r=0; r<4; r++){
        int qrow = wid*16 + (lane>>4)*4 + r;
        Ps[kc*512 + qrow*8 + krm] = f2bf(sfr[ni][r]);
      }
    }
    #pragma unroll
    for (int ks = 0; ks < 2; ks++){
      int kc = ks*4 + (lane >> 4);
      bf16x8 afr = *(const bf16x8*)&Ps[kc*512 + (wid*16 + (lane&15))*8];
      #pragma unroll
      for (int ci=0; ci<4; ci++){
        bf16x8 bfr = *(const bf16x8*)&Vt[kc*512 + (ci*16 + (lane&15))*8];
        o[ci] = __builtin_amdgcn_mfma_f32_16x16x32_bf16(afr, bfr, o[ci], 0,0,0);
      }
    }
  }

  int b_ = bh / H_, h = bh % H_;
  #pragma unroll
  for (int ci=0; ci<4; ci++){
    int d = h*64 + ci*16 + (lane&15);
    #pragma unroll
    for (int r=0; r<4; r++){
      int srow = qt*64 + wid*16 + (lane>>4)*4 + r;
      attn[((size_t)b_*S_ + srow)*D_ + d] = o[ci][r] / lrow[r];
    }
  }
}

// ============ 256x256 GEMM on TILED operands ============
// A, Bt in tiled layout (toff): staging = linear 16KB chunk copy per K-step.
// BK=32, ring-3 LDS (96KB), counted vmcnt(4) 2-phase cover, 2D XCD patches.
// EPI 0: gelu -> bf16 TILED (consumer K = N)   EPI 1: + addin -> fp32 row-major
template<int K_, int EPI, int PM, int PN, int PGN>
__global__ __launch_bounds__(512, 2) void gemm256_kernel(
    const u16* __restrict__ A, const u16* __restrict__ Bt,
    const float* __restrict__ bias, void* __restrict__ outp,
    const float* __restrict__ addin, int N){
  constexpr int NT = K_/32;                     // K-steps
  __shared__ __align__(16) u16 As[3*8192];      // [slot][4 kc][256 m][8]  48KB
  __shared__ __align__(16) u16 Bs[3*8192];      // [slot][4 kc][256 n][8]  48KB
  int tid = threadIdx.x, lane = tid & 63, wid = tid >> 6;
  int wm = wid >> 2, wn = wid & 3;              // 2x4 waves
  int bid = blockIdx.x;
  int j = bid >> 3, xcd = bid & 7;
  int bm = (xcd/PGN)*PM + (j - (j/PM)*PM);
  int bn = (xcd - (xcd/PGN)*PGN)*PN + (j/PM);
  const u16* Ab = A  + (size_t)bm*256*K_;       // tiled panel base
  const u16* Bb = Bt + (size_t)bn*256*K_;

  auto stage = [&](int slot, int kt){           // linear copy: 2x16KB chunks
    const u16* Asrc = Ab + (size_t)kt*8192;
    const u16* Bsrc = Bb + (size_t)kt*8192;
    #pragma unroll
    for (int r = 0; r < 2; r++){
      int u0 = r*512 + wid*64;                  // wave-uniform; +lane by HW
      gload16(Asrc + (size_t)(u0 + lane)*8, &As[slot*8192 + u0*8]);
      gload16(Bsrc + (size_t)(u0 + lane)*8, &Bs[slot*8192 + u0*8]);
    }
  };

  f32x4 acc[8][4];
  #pragma unroll
  for (int mi=0; mi<8; mi++)
    #pragma unroll
    for (int ni=0; ni<4; ni++) acc[mi][ni] = (f32x4){0.f,0.f,0.f,0.f};

  // prologue: slot0 <- step0, slot1 <- step1; drain batch0
  stage(0, 0); stage(1, 1);
  asm volatile("s_waitcnt vmcnt(4)" ::: "memory");
  __builtin_amdgcn_s_barrier();

  for (int k = 0; k < NT; k++){
    int slot = k - (k/3)*3;                     // k % 3
    int snx  = (k+2) - ((k+2)/3)*3;             // (k+2) % 3
    int ksrc = (k+2 < NT) ? (k+2) : (NT-1);     // clamp-restage at tail
    stage(snx, ksrc);

    bf16x8 af[8], bfv[4];
    int kc = lane >> 4;
    #pragma unroll
    for (int mi=0; mi<8; mi++)
      af[mi] = *(const bf16x8*)&As[slot*8192 + kc*2048 + (wm*128 + mi*16 + (lane&15))*8];
    #pragma unroll
    for (int ni=0; ni<4; ni++)
      bfv[ni] = *(const bf16x8*)&Bs[slot*8192 + kc*2048 + (wn*64 + ni*16 + (lane&15))*8];
    asm volatile("s_waitcnt lgkmcnt(0)" ::: "memory");
    __builtin_amdgcn_sched_barrier(0);
    __builtin_amdgcn_s_setprio(1);
    #pragma unroll
    for (int mi=0; mi<8; mi++)
      #pragma unroll
      for (int ni=0; ni<4; ni++)
        acc[mi][ni] = __builtin_amdgcn_mfma_f32_16x16x32_bf16(af[mi], bfv[ni], acc[mi][ni], 0,0,0);
    __builtin_amdgcn_s_setprio(0);
    asm volatile("s_waitcnt vmcnt(4)" ::: "memory");   // drain batch k+1 for next phase
    __builtin_amdgcn_s_barrier();
  }

  int gm0 = bm*256 + wm*128, gn0 = bn*256 + wn*64;
  #pragma unroll
  for (int mi=0; mi<8; mi++){
    #pragma unroll
    for (int ni=0; ni<4; ni++){
      int gn = gn0 + ni*16 + (lane&15);
      float bb = bias[gn];
      #pragma unroll
      for (int r=0; r<4; r++){
        int gm = gm0 + mi*16 + (lane>>4)*4 + r;
        float val = acc[mi][ni][r] + bb;
        if (EPI == 0){
          float ge = 0.5f*val*(1.f + erff(val*0.70710678118f));
          ((u16*)outp)[toff(gm, gn, N)] = f2bf(ge);   // tiled for next GEMM
        } else {
          ((float*)outp)[(size_t)gm*N + gn] = val + addin[(size_t)gm*N + gn];
        }
      }
    }
  }
}

extern "C" void kernel_launch(void* const* d_in, const int* in_sizes, int n_in,
                              void* d_out, int out_size, void* d_ws, size_t ws_size,
                              hipStream_t stream) {
  const float* x   = (const float*)d_in[0];
  const float* lng = (const float*)d_in[1];
  const float* lnb = (const float*)d_in[2];
  const float* Wq  = (const float*)d_in[3];
  const float* bq  = (const float*)d_in[4];
  const float* Wk  = (const float*)d_in[5];
  const float* bk  = (const float*)d_in[6];
  const float* Wv  = (const float*)d_in[7];
  const float* bv  = (const float*)d_in[8];
  const float* W1  = (const float*)d_in[9];
  const float* b1  = (const float*)d_in[10];
  const float* Wm  = (const float*)d_in[11];
  const float* bm  = (const float*)d_in[12];
  const float* W2  = (const float*)d_in[13];
  const float* b2  = (const float*)d_in[14];
  float* out = (float*)d_out;

  char* ws = (char*)d_ws;
  const size_t MB = 1024*1024;
  u16*   n1  = (u16*)(ws + 0);          // 12 MiB  (reused as n2) [tiled K=768]
  u16*   qq  = (u16*)(ws + 12*MB);      // 12 MiB
  u16*   kk  = (u16*)(ws + 24*MB);      // 12 MiB
  u16*   vv  = (u16*)(ws + 36*MB);      // 12 MiB
  float* at  = (float*)(ws + 48*MB);    // 24 MiB
  u16*   h1  = (u16*)(ws + 12*MB);      // 48 MiB [tiled K=3072] (overlays qkv+attn)
  u16*   h2  = (u16*)(ws + 72*MB);      // 48 MiB [tiled K=3072]
  u16*   w1t = (u16*)(ws + 120*MB);     // 4.5 MiB [tiled N=3072,K=768]
  u16*   wmt = (u16*)(ws + 125*MB);     // 18 MiB  [tiled N=3072,K=3072]
  u16*   w2t = (u16*)(ws + 144*MB);     // 4.5 MiB [tiled N=768, K=3072]

  transpose_cast<<<dim3(F_/32, D_/32), dim3(32,8), 0, stream>>>(W1, w1t, D_, F_);
  transpose_cast<<<dim3(F_/32, F_/32), dim3(32,8), 0, stream>>>(Wm, wmt, F_, F_);
  transpose_cast<<<dim3(D_/32, F_/32), dim3(32,8), 0, stream>>>(W2, w2t, F_, D_);

  ln_kernel<<<NR, 256, 0, stream>>>(x, lng, lnb, n1);
  qkv_kernel<<<dim3(NR/64, H_), 256, 0, stream>>>(n1, Wq, bq, Wk, bk, Wv, bv, qq, kk, vv);
  attn_kernel<<<dim3(S_/64, B_*H_), 256, 0, stream>>>(qq, kk, vv, at);
  midln_kernel<<<NR, 256, 0, stream>>>(x, at, lng, lnb, out, n1 /*=n2*/);

  // M=8192 -> 32 tiles; N=3072 -> 12 (patch 8x6, PGN=2); N=768 -> 3 (patch 4x3, PGN=1)
  gemm256_kernel<768, 0, 8, 6, 2><<<384, 512, 0, stream>>>(n1, w1t, b1, h1, nullptr, F_);
  gemm256_kernel<3072,0, 8, 6, 2><<<384, 512, 0, stream>>>(h1, wmt, bm, h2, nullptr, F_);
  gemm256_kernel<3072,1, 4, 3, 1><<<96,  512, 0, stream>>>(h2, w2t, b2, out, out, D_);
}

// Round 8
// 761.440 us; speedup vs baseline: 1.3546x; 1.0178x over previous
//
#include <hip/hip_runtime.h>
#include <hip/hip_bf16.h>
#include <cmath>
#include <cstdint>

#define B_ 8
#define S_ 1024
#define D_ 768
#define H_ 12
#define C_ 64
#define F_ 3072
#define NR (B_*S_)          // 8192 rows
#define LN_EPS 1e-5f

typedef unsigned short u16;                                  // bf16 bit-storage
typedef float  f32x4  __attribute__((ext_vector_type(4)));
typedef short  bf16x8 __attribute__((ext_vector_type(8)));   // 8 bf16 = 4 VGPR

__device__ __forceinline__ u16 f2bf(float f){
  __hip_bfloat16 h = __float2bfloat16(f);
  return *reinterpret_cast<u16*>(&h);
}

// Tiled operand layout: global image == LDS staging image (verified r7: +71%).
// offset(m,k) = panel(m)*256K + kstep(k)*8192 + kc(k)*2048 + (m%256)*8 + k%8
__device__ __forceinline__ size_t toff(int m, int k, int K){
  return (size_t)(m>>8)*((size_t)K*256) + (size_t)(k>>5)*8192
       + (size_t)((k>>3)&3)*2048 + (size_t)(m&255)*8 + (size_t)(k&7);
}

// async global->LDS, 16B per lane; LDS dest is wave-uniform base + lane*16
__device__ __forceinline__ void gload16(const void* g, void* l){
  __builtin_amdgcn_global_load_lds(
      (const __attribute__((address_space(1))) void*)g,
      (__attribute__((address_space(3))) void*)l, 16, 0, 0);
}

__device__ __forceinline__ void blk_reduce2(float& s, float& sq, float* red){
  #pragma unroll
  for (int o = 32; o > 0; o >>= 1){
    s  += __shfl_down(s,  o, 64);
    sq += __shfl_down(sq, o, 64);
  }
  int w = threadIdx.x >> 6;
  if ((threadIdx.x & 63) == 0){ red[w] = s; red[4+w] = sq; }
  __syncthreads();
  s  = red[0]+red[1]+red[2]+red[3];
  sq = red[4]+red[5]+red[6]+red[7];
}

// ---------------- LN: x -> n1 (bf16, tiled K=768) ----------------
__global__ __launch_bounds__(256) void ln_kernel(const float* __restrict__ x,
    const float* __restrict__ g, const float* __restrict__ b,
    u16* __restrict__ n1){
  int row = blockIdx.x;
  size_t base = (size_t)row * D_;
  __shared__ float red[8];
  float v[3], s = 0.f, sq = 0.f;
  #pragma unroll
  for (int i = 0; i < 3; i++){
    int j = threadIdx.x + i*256;
    float t = x[base + j];
    v[i] = t; s += t; sq += t*t;
  }
  blk_reduce2(s, sq, red);
  float mean = s * (1.f/D_);
  float var  = sq * (1.f/D_) - mean*mean;
  float rstd = rsqrtf(var + LN_EPS);
  #pragma unroll
  for (int i = 0; i < 3; i++){
    int j = threadIdx.x + i*256;
    n1[toff(row, j, D_)] = f2bf((v[i]-mean)*rstd*g[j] + b[j]);
  }
}

// ---- middle = x + attn -> d_out(fp32);  LN(middle) -> n2 (bf16, tiled) ----
__global__ __launch_bounds__(256) void midln_kernel(const float* __restrict__ x,
    const float* __restrict__ attn, const float* __restrict__ g,
    const float* __restrict__ b, float* __restrict__ mid, u16* __restrict__ n2){
  int row = blockIdx.x;
  size_t base = (size_t)row * D_;
  __shared__ float red[8];
  float v[3], s = 0.f, sq = 0.f;
  #pragma unroll
  for (int i = 0; i < 3; i++){
    int j = threadIdx.x + i*256;
    float t = x[base + j] + attn[base + j];
    mid[base + j] = t;
    v[i] = t; s += t; sq += t*t;
  }
  blk_reduce2(s, sq, red);
  float mean = s * (1.f/D_);
  float var  = sq * (1.f/D_) - mean*mean;
  float rstd = rsqrtf(var + LN_EPS);
  #pragma unroll
  for (int i = 0; i < 3; i++){
    int j = threadIdx.x + i*256;
    n2[toff(row, j, D_)] = f2bf((v[i]-mean)*rstd*g[j] + b[j]);
  }
}

// ------------- W[K][N] fp32 -> Wt tiled [N][K] bf16 -------------
__global__ void transpose_cast(const float* __restrict__ W, u16* __restrict__ Wt,
                               int K, int N){
  __shared__ float t[32][33];
  int n0 = blockIdx.x*32, k0 = blockIdx.y*32;
  for (int i = threadIdx.y; i < 32; i += 8)
    t[i][threadIdx.x] = W[(size_t)(k0+i)*N + n0 + threadIdx.x];
  __syncthreads();
  for (int i = threadIdx.y; i < 32; i += 8)
    Wt[toff(n0+i, k0+threadIdx.x, K)] = f2bf(t[threadIdx.x][i]);
}

// ---------------- per-head QKV projection (MFMA) ----------------
__global__ __launch_bounds__(256) void qkv_kernel(const u16* __restrict__ n1,
    const float* __restrict__ Wq, const float* __restrict__ bq,
    const float* __restrict__ Wk, const float* __restrict__ bk,
    const float* __restrict__ Wv, const float* __restrict__ bv,
    u16* __restrict__ q, u16* __restrict__ k, u16* __restrict__ v){
  int rt = blockIdx.x;           // 128 row-tiles of 64 rows
  int h  = blockIdx.y;           // head
  int tid = threadIdx.x, lane = tid & 63, wid = tid >> 6;
  __shared__ __align__(16) u16 Xs[4096];       // [8 kc][64 m][8]
  __shared__ __align__(16) u16 Ws[3*4096];     // per mat: [8 kc(d)][64 c][8]

  #pragma unroll
  for (int mat = 0; mat < 3; mat++){
    const float* Wh = (mat==0?Wq:(mat==1?Wk:Wv)) + (size_t)h*4096;
    for (int e = 0; e < 16; e++){
      int flat = e*256 + tid;            // d*64+c
      int d = flat >> 6, c = flat & 63;
      Ws[mat*4096 + (d>>3)*512 + c*8 + (d&7)] = f2bf(Wh[flat]);
    }
  }
  // X tile rows rt*64..rt*64+63, cols h*64+kc*8..+7 from tiled n1
  for (int r = 0; r < 2; r++){
    int u0 = (r*4 + wid)*64;
    int kc = u0 >> 6;                    // uniform per call; m = lane
    gload16(n1 + (size_t)(rt>>2)*196608 + (size_t)(h*2 + (kc>>2))*8192
               + (size_t)(kc&3)*2048 + (size_t)((rt&3)*64 + lane)*8,
            &Xs[u0*8]);
  }
  __syncthreads();

  f32x4 acc[4][3];
  #pragma unroll
  for (int mi=0; mi<4; mi++)
    #pragma unroll
    for (int ni=0; ni<3; ni++) acc[mi][ni] = (f32x4){0.f,0.f,0.f,0.f};

  #pragma unroll
  for (int ks = 0; ks < 2; ks++){
    int kc = ks*4 + (lane >> 4);
    bf16x8 a[4], bfr[3];
    #pragma unroll
    for (int mi=0; mi<4; mi++)
      a[mi] = *(const bf16x8*)&Xs[kc*512 + (mi*16 + (lane&15))*8];
    #pragma unroll
    for (int ni=0; ni<3; ni++){
      int co = wid*48 + ni*16 + (lane&15);   // col in concat(q,k,v) 0..191
      int mat = co >> 6, c = co & 63;
      bfr[ni] = *(const bf16x8*)&Ws[mat*4096 + kc*512 + c*8];
    }
    #pragma unroll
    for (int mi=0; mi<4; mi++)
      #pragma unroll
      for (int ni=0; ni<3; ni++)
        acc[mi][ni] = __builtin_amdgcn_mfma_f32_16x16x32_bf16(a[mi], bfr[ni], acc[mi][ni], 0,0,0);
  }

  #pragma unroll
  for (int ni=0; ni<3; ni++){
    int co = wid*48 + ni*16 + (lane&15);
    int mat = co >> 6, c = co & 63;
    u16* outp = mat==0 ? q : (mat==1 ? k : v);
    const float* bias = mat==0 ? bq : (mat==1 ? bk : bv);
    float bb = bias[h*64 + c];
    #pragma unroll
    for (int mi=0; mi<4; mi++){
      #pragma unroll
      for (int r=0; r<4; r++){
        int grow = rt*64 + mi*16 + (lane>>4)*4 + r;   // 0..8191
        int b_ = grow >> 10, s = grow & 1023;
        outp[(((size_t)b_*H_ + h)*S_ + s)*C_ + c] = f2bf(acc[mi][ni][r] + bb);
      }
    }
  }
}

// ---------------- flash attention (bf16 MFMA, fp32 online softmax) ----------------
__global__ __launch_bounds__(256) void attn_kernel(const u16* __restrict__ q,
    const u16* __restrict__ k, const u16* __restrict__ v, float* __restrict__ attn){
  int qt = blockIdx.x, bh = blockIdx.y;
  int tid = threadIdx.x, lane = tid & 63, wid = tid >> 6;
  __shared__ __align__(16) u16 Qs[4096], Ks[4096], Vt[4096], Ps[4096];
  const u16* qh = q + (size_t)bh*S_*C_;
  const u16* kh = k + (size_t)bh*S_*C_;
  const u16* vh = v + (size_t)bh*S_*C_;

  for (int r = 0; r < 2; r++){
    int u0 = (r*4 + wid)*64;
    int u = u0 + lane, kc = u >> 6, m = u & 63;
    gload16(qh + (size_t)(qt*64 + m)*C_ + kc*8, &Qs[u0*8]);
  }

  f32x4 o[4];
  #pragma unroll
  for (int ci=0; ci<4; ci++) o[ci] = (f32x4){0.f,0.f,0.f,0.f};
  float mrow[4] = {-1e30f,-1e30f,-1e30f,-1e30f};
  float lrow[4] = {0.f,0.f,0.f,0.f};

  for (int kt = 0; kt < S_/64; kt++){
    __syncthreads();
    for (int r = 0; r < 2; r++){
      int u0 = (r*4 + wid)*64;
      int u = u0 + lane, kc = u >> 6, m = u & 63;
      gload16(kh + (size_t)(kt*64 + m)*C_ + kc*8, &Ks[u0*8]);
    }
    for (int i = 0; i < 2; i++){
      int cc = i*256 + tid;                 // 512 chunks of 8
      int kk2 = cc >> 3, c0 = (cc & 7)*8;
      bf16x8 vv8 = *(const bf16x8*)&vh[(size_t)(kt*64 + kk2)*C_ + c0];
      #pragma unroll
      for (int j = 0; j < 8; j++)
        Vt[(kk2>>3)*512 + (c0+j)*8 + (kk2&7)] = ((const u16*)&vv8)[j];
    }
    __syncthreads();

    f32x4 sfr[4];
    #pragma unroll
    for (int ni=0; ni<4; ni++) sfr[ni] = (f32x4){0.f,0.f,0.f,0.f};
    #pragma unroll
    for (int ks = 0; ks < 2; ks++){
      int kc = ks*4 + (lane >> 4);
      bf16x8 afr = *(const bf16x8*)&Qs[kc*512 + (wid*16 + (lane&15))*8];
      #pragma unroll
      for (int ni=0; ni<4; ni++){
        bf16x8 bfr = *(const bf16x8*)&Ks[kc*512 + (ni*16 + (lane&15))*8];
        sfr[ni] = __builtin_amdgcn_mfma_f32_16x16x32_bf16(afr, bfr, sfr[ni], 0,0,0);
      }
    }

    float alpha[4];
    #pragma unroll
    for (int r = 0; r < 4; r++){
      float mx = -1e30f;
      #pragma unroll
      for (int ni=0; ni<4; ni++){ sfr[ni][r] *= 0.125f; mx = fmaxf(mx, sfr[ni][r]); }
      #pragma unroll
      for (int off = 1; off < 16; off <<= 1) mx = fmaxf(mx, __shfl_xor(mx, off, 64));
      float mnew = fmaxf(mrow[r], mx);
      alpha[r] = __expf(mrow[r] - mnew);
      mrow[r] = mnew;
      float rs = 0.f;
      #pragma unroll
      for (int ni=0; ni<4; ni++){
        float p = __expf(sfr[ni][r] - mnew);
        sfr[ni][r] = p; rs += p;
      }
      #pragma unroll
      for (int off = 1; off < 16; off <<= 1) rs += __shfl_xor(rs, off, 64);
      lrow[r] = lrow[r]*alpha[r] + rs;
    }
    #pragma unroll
    for (int ci=0; ci<4; ci++)
      #pragma unroll
      for (int r=0; r<4; r++) o[ci][r] *= alpha[r];

    #pragma unroll
    for (int ni=0; ni<4; ni++){
      int kcol = ni*16 + (lane&15);
      int kc = kcol >> 3, krm = kcol & 7;
      #pragma unroll
      for (int r=0; r<4; r++){
        int qrow = wid*16 + (lane>>4)*4 + r;
        Ps[kc*512 + qrow*8 + krm] = f2bf(sfr[ni][r]);
      }
    }
    #pragma unroll
    for (int ks = 0; ks < 2; ks++){
      int kc = ks*4 + (lane >> 4);
      bf16x8 afr = *(const bf16x8*)&Ps[kc*512 + (wid*16 + (lane&15))*8];
      #pragma unroll
      for (int ci=0; ci<4; ci++){
        bf16x8 bfr = *(const bf16x8*)&Vt[kc*512 + (ci*16 + (lane&15))*8];
        o[ci] = __builtin_amdgcn_mfma_f32_16x16x32_bf16(afr, bfr, o[ci], 0,0,0);
      }
    }
  }

  int b_ = bh / H_, h = bh % H_;
  #pragma unroll
  for (int ci=0; ci<4; ci++){
    int d = h*64 + ci*16 + (lane&15);
    #pragma unroll
    for (int r=0; r<4; r++){
      int srow = qt*64 + wid*16 + (lane>>4)*4 + r;
      attn[((size_t)b_*S_ + srow)*D_ + d] = o[ci][r] / lrow[r];
    }
  }
}

// ============ 256x256 GEMM on TILED operands, ring-4 pipeline ============
// Ring-4 LDS (128KB): stage step k+3 at phase k, vmcnt(12) = 3-phase latency
// cover (~5000cyc >> HBM tail). Slot k%4 overwritten at phase k+1 only after
// phase-k's end barrier. SPLIT-K: grid = SPLIT*NBLK; chunk c covers steps
// [c*NSTEP, (c+1)*NSTEP); EPI2 writes fp32 partial at chunk offset.
// EPI 0: gelu -> bf16 TILED   EPI 1: +addin -> fp32   EPI 2: fp32 partial
template<int KPAN, int NSTEP, int NBLK, int EPI, int PM, int PN, int PGN>
__global__ __launch_bounds__(512, 2) void gemm256_kernel(
    const u16* __restrict__ A, const u16* __restrict__ Bt,
    const float* __restrict__ bias, void* __restrict__ outp,
    const float* __restrict__ addin, int N){
  __shared__ __align__(16) u16 As[4*8192];      // [slot][4 kc][256 m][8]  64KB
  __shared__ __align__(16) u16 Bs[4*8192];      // [slot][4 kc][256 n][8]  64KB
  int tid = threadIdx.x, lane = tid & 63, wid = tid >> 6;
  int wm = wid >> 2, wn = wid & 3;              // 2x4 waves
  int bid = blockIdx.x;
  int chunk = bid / NBLK;                       // split-K chunk
  int bidc  = bid - chunk*NBLK;
  int j = bidc >> 3, xcd = bidc & 7;
  int bm = (xcd/PGN)*PM + (j - (j/PM)*PM);
  int bn = (xcd - (xcd/PGN)*PGN)*PN + (j/PM);
  int kbase = chunk * NSTEP;
  const u16* Ab = A  + (size_t)bm*256*KPAN;     // tiled panel base
  const u16* Bb = Bt + (size_t)bn*256*KPAN;

  auto stage = [&](int slot, int kt){           // kt = global K-step; 4 gloads
    const u16* Asrc = Ab + (size_t)kt*8192;
    const u16* Bsrc = Bb + (size_t)kt*8192;
    #pragma unroll
    for (int r = 0; r < 2; r++){
      int u0 = r*512 + wid*64;                  // wave-uniform; +lane by HW
      gload16(Asrc + (size_t)(u0 + lane)*8, &As[slot*8192 + u0*8]);
      gload16(Bsrc + (size_t)(u0 + lane)*8, &Bs[slot*8192 + u0*8]);
    }
  };

  f32x4 acc[8][4];
  #pragma unroll
  for (int mi=0; mi<8; mi++)
    #pragma unroll
    for (int ni=0; ni<4; ni++) acc[mi][ni] = (f32x4){0.f,0.f,0.f,0.f};

  // prologue: slots 0..2 <- steps 0..2 (clamped)
  stage(0, kbase);
  stage(1, kbase + ((1 < NSTEP) ? 1 : NSTEP-1));
  stage(2, kbase + ((2 < NSTEP) ? 2 : NSTEP-1));

  for (int k = 0; k < NSTEP; k++){
    int slot = k & 3;
    int t3 = (k+3 < NSTEP) ? (k+3) : (NSTEP-1); // clamp-restage at tail
    stage((k+3) & 3, kbase + t3);

    asm volatile("s_waitcnt vmcnt(12)" ::: "memory");  // step k landed (this wave)
    __builtin_amdgcn_s_barrier();                      // all waves' step k in LDS

    bf16x8 af[8], bfv[4];
    int kc = lane >> 4;
    #pragma unroll
    for (int mi=0; mi<8; mi++)
      af[mi] = *(const bf16x8*)&As[slot*8192 + kc*2048 + (wm*128 + mi*16 + (lane&15))*8];
    #pragma unroll
    for (int ni=0; ni<4; ni++)
      bfv[ni] = *(const bf16x8*)&Bs[slot*8192 + kc*2048 + (wn*64 + ni*16 + (lane&15))*8];
    asm volatile("s_waitcnt lgkmcnt(0)" ::: "memory");
    __builtin_amdgcn_sched_barrier(0);
    __builtin_amdgcn_s_setprio(1);
    #pragma unroll
    for (int mi=0; mi<8; mi++)
      #pragma unroll
      for (int ni=0; ni<4; ni++)
        acc[mi][ni] = __builtin_amdgcn_mfma_f32_16x16x32_bf16(af[mi], bfv[ni], acc[mi][ni], 0,0,0);
    __builtin_amdgcn_s_setprio(0);
    __builtin_amdgcn_s_barrier();                      // readers done -> slot reusable
  }
  asm volatile("s_waitcnt vmcnt(0)" ::: "memory");

  int gm0 = bm*256 + wm*128, gn0 = bn*256 + wn*64;
  #pragma unroll
  for (int mi=0; mi<8; mi++){
    #pragma unroll
    for (int ni=0; ni<4; ni++){
      int gn = gn0 + ni*16 + (lane&15);
      float bb = (EPI == 2) ? 0.f : bias[gn];
      #pragma unroll
      for (int r=0; r<4; r++){
        int gm = gm0 + mi*16 + (lane>>4)*4 + r;
        float val = acc[mi][ni][r] + bb;
        if (EPI == 0){
          float ge = 0.5f*val*(1.f + erff(val*0.70710678118f));
          ((u16*)outp)[toff(gm, gn, N)] = f2bf(ge);   // tiled for next GEMM
        } else if (EPI == 1){
          ((float*)outp)[(size_t)gm*N + gn] = val + addin[(size_t)gm*N + gn];
        } else {
          ((float*)outp)[(size_t)chunk*((size_t)NR*N) + (size_t)gm*N + gn] = val;
        }
      }
    }
  }
}

// ---- split-K reduce: out = middle(out) + p0+p1+p2 + bias ----
__global__ __launch_bounds__(256) void reduce3_kernel(const float* __restrict__ p,
    const float* __restrict__ bias, float* __restrict__ out){
  size_t i = ((size_t)blockIdx.x*256 + threadIdx.x)*4;
  const size_t CH = (size_t)NR*D_;
  f32x4 a = *(const f32x4*)&p[i];
  f32x4 b = *(const f32x4*)&p[i+CH];
  f32x4 c = *(const f32x4*)&p[i+2*CH];
  f32x4 m = *(const f32x4*)&out[i];
  int gn = (int)(i % D_);
  f32x4 bb = *(const f32x4*)&bias[gn];
  *(f32x4*)&out[i] = m + a + b + c + bb;
}

extern "C" void kernel_launch(void* const* d_in, const int* in_sizes, int n_in,
                              void* d_out, int out_size, void* d_ws, size_t ws_size,
                              hipStream_t stream) {
  const float* x   = (const float*)d_in[0];
  const float* lng = (const float*)d_in[1];
  const float* lnb = (const float*)d_in[2];
  const float* Wq  = (const float*)d_in[3];
  const float* bq  = (const float*)d_in[4];
  const float* Wk  = (const float*)d_in[5];
  const float* bk  = (const float*)d_in[6];
  const float* Wv  = (const float*)d_in[7];
  const float* bv  = (const float*)d_in[8];
  const float* W1  = (const float*)d_in[9];
  const float* b1  = (const float*)d_in[10];
  const float* Wm  = (const float*)d_in[11];
  const float* bm  = (const float*)d_in[12];
  const float* W2  = (const float*)d_in[13];
  const float* b2  = (const float*)d_in[14];
  float* out = (float*)d_out;

  char* ws = (char*)d_ws;
  const size_t MB = 1024*1024;
  u16*   n1  = (u16*)(ws + 0);          // 12 MiB  (reused as n2) [tiled K=768]
  u16*   qq  = (u16*)(ws + 12*MB);      // 12 MiB
  u16*   kk  = (u16*)(ws + 24*MB);      // 12 MiB
  u16*   vv  = (u16*)(ws + 36*MB);      // 12 MiB
  float* at  = (float*)(ws + 48*MB);    // 24 MiB
  u16*   h1  = (u16*)(ws + 12*MB);      // 48 MiB [tiled K=3072] (overlays qkv+attn)
  u16*   h2  = (u16*)(ws + 72*MB);      // 48 MiB [tiled K=3072]
  u16*   w1t = (u16*)(ws + 120*MB);     // 4.5 MiB [tiled N=3072,K=768]
  u16*   wmt = (u16*)(ws + 125*MB);     // 18 MiB  [tiled N=3072,K=3072]
  u16*   w2t = (u16*)(ws + 144*MB);     // 4.5 MiB [tiled N=768, K=3072]
  float* pk  = (float*)(ws + 0);        // 3x24 MiB split-K partials (n1/qkv/at dead)

  transpose_cast<<<dim3(F_/32, D_/32), dim3(32,8), 0, stream>>>(W1, w1t, D_, F_);
  transpose_cast<<<dim3(F_/32, F_/32), dim3(32,8), 0, stream>>>(Wm, wmt, F_, F_);
  transpose_cast<<<dim3(D_/32, F_/32), dim3(32,8), 0, stream>>>(W2, w2t, F_, D_);

  ln_kernel<<<NR, 256, 0, stream>>>(x, lng, lnb, n1);
  qkv_kernel<<<dim3(NR/64, H_), 256, 0, stream>>>(n1, Wq, bq, Wk, bk, Wv, bv, qq, kk, vv);
  attn_kernel<<<dim3(S_/64, B_*H_), 256, 0, stream>>>(qq, kk, vv, at);
  midln_kernel<<<NR, 256, 0, stream>>>(x, at, lng, lnb, out, n1 /*=n2*/);

  // GEMM-1: 32x12 tiles (patch 8x6); GEMM-m: same; GEMM-2: 32x3 tiles x 3 K-chunks
  gemm256_kernel<768, 24, 384, 0, 8, 6, 2><<<384, 512, 0, stream>>>(n1, w1t, b1, h1, nullptr, F_);
  gemm256_kernel<3072, 96, 384, 0, 8, 6, 2><<<384, 512, 0, stream>>>(h1, wmt, bm, h2, nullptr, F_);
  gemm256_kernel<3072, 32, 96, 2, 4, 3, 1><<<288, 512, 0, stream>>>(h2, w2t, nullptr, pk, nullptr, D_);
  reduce3_kernel<<<NR*D_/1024, 256, 0, stream>>>(pk, b2, out);
}